// Round 10
// baseline (178.369 us; speedup 1.0000x reference)
//
#include <hip/hip_runtime.h>
#include <math.h>

#define BSZ 16
#define SEQ 2048
#define DKD 64
#define NTH 256

typedef __attribute__((ext_vector_type(8))) short bf16x8;
typedef __attribute__((ext_vector_type(8))) short short8;
typedef __attribute__((ext_vector_type(4))) float f32x4;

__device__ __forceinline__ short f2bf(float x) {
  union { float f; unsigned u; } c; c.f = x;
  unsigned r = c.u + 0x7fffu + ((c.u >> 16) & 1u);
  return (short)(r >> 16);
}

// pack two floats' bf16-truncations into one int: low short = lo, high short = hi
__device__ __forceinline__ int pkbf(float hi, float lo) {
  return (int)__builtin_amdgcn_perm(__float_as_uint(hi), __float_as_uint(lo), 0x07060302u);
}

// async 16B/lane global->LDS DMA; ldst wave-uniform, lane i lands at ldst + i*16
#define GLD16(gsrc, ldst)                                                                  \
  __builtin_amdgcn_global_load_lds((const __attribute__((address_space(1))) void*)(gsrc), \
                                   (__attribute__((address_space(3))) void*)(ldst), 16, 0, 0)

// XOR chunk swizzle: logical (row, 16B-chunk c8) -> physical chunk index
#define CH(row, c8) (((row) << 3) + ((c8) ^ ((row) & 7)))

// ws layout: Kbf [16][2048][64] @ 0         (4,194,304 B)
//            VT  [16][64][2048] @ 4194304   (4,194,304 B; keys sigma-permuted per 32)
//            PT  [2176][64]     @ 8388608   (278,528 B; rows 2048..2175 zero)
//            L   [16][2048] f32 @ 8667136   (131,072 B)   total 8,798,208 B

// ---------- node 1: bf16 convert K, transpose+convert V and P, zero O/L ----------
__launch_bounds__(NTH)
__global__ void pre_convert(const float* __restrict__ K, const float* __restrict__ V,
                            const float* __restrict__ P, short* __restrict__ Kbf,
                            short* __restrict__ VTbf, short* __restrict__ PTbf,
                            float* __restrict__ Ozero, float* __restrict__ Lzero) {
  __shared__ short T[64 * 65];
  const int blk = blockIdx.x;
  const int tid = threadIdx.x;
  if (blk < 1024) {
    // K convert (stream) + V transpose, 32-row chunk
    const int b = blk >> 6, ch = blk & 63;
    const float* Kb = K + ((size_t)(b * SEQ + ch * 32)) * DKD;
    const float* Vb = V + ((size_t)(b * SEQ + ch * 32)) * DKD;
    const int r = tid >> 3, c8 = (tid & 7) << 3;
    float4 a0 = *(const float4*)(Kb + r * DKD + c8);
    float4 a1 = *(const float4*)(Kb + r * DKD + c8 + 4);
    short8 ko;
    ko[0] = f2bf(a0.x); ko[1] = f2bf(a0.y); ko[2] = f2bf(a0.z); ko[3] = f2bf(a0.w);
    ko[4] = f2bf(a1.x); ko[5] = f2bf(a1.y); ko[6] = f2bf(a1.z); ko[7] = f2bf(a1.w);
    *(short8*)(Kbf + ((size_t)(b * SEQ + ch * 32 + r)) * DKD + c8) = ko;
    float4 v0 = *(const float4*)(Vb + r * DKD + c8);
    float4 v1 = *(const float4*)(Vb + r * DKD + c8 + 4);
    T[(c8 + 0) * 33 + r] = f2bf(v0.x); T[(c8 + 1) * 33 + r] = f2bf(v0.y);
    T[(c8 + 2) * 33 + r] = f2bf(v0.z); T[(c8 + 3) * 33 + r] = f2bf(v0.w);
    T[(c8 + 4) * 33 + r] = f2bf(v1.x); T[(c8 + 5) * 33 + r] = f2bf(v1.y);
    T[(c8 + 6) * 33 + r] = f2bf(v1.z); T[(c8 + 7) * 33 + r] = f2bf(v1.w);
    __syncthreads();
    // sigma-permuted write: out positions qg*8+j hold keys {4qg..4qg+3, 16+4qg..16+4qg+3}
    const int d = tid >> 2, qg = tid & 3;
    short8 w;
    #pragma unroll
    for (int j = 0; j < 4; ++j) {
      w[j]     = T[d * 33 + qg * 4 + j];
      w[4 + j] = T[d * 33 + 16 + qg * 4 + j];
    }
    *(short8*)(VTbf + ((size_t)(b * DKD + d)) * SEQ + ch * 32 + qg * 8) = w;
  } else if (blk < 1056) {
    const int c0 = (blk - 1024) * 64;
    const int d = tid >> 2, cc4 = (tid & 3) << 4;
    #pragma unroll
    for (int j4 = 0; j4 < 4; ++j4) {
      const int c = cc4 + j4 * 4;
      float4 pv = *(const float4*)(P + (size_t)d * SEQ + c0 + c);
      T[(c + 0) * 65 + d] = f2bf(pv.x);
      T[(c + 1) * 65 + d] = f2bf(pv.y);
      T[(c + 2) * 65 + d] = f2bf(pv.z);
      T[(c + 3) * 65 + d] = f2bf(pv.w);
    }
    __syncthreads();
    const int c = tid >> 2, d4 = (tid & 3) << 4;
    short8 w0, w1;
    #pragma unroll
    for (int j = 0; j < 8; ++j) { w0[j] = T[c * 65 + d4 + j]; w1[j] = T[c * 65 + d4 + 8 + j]; }
    short* Po = PTbf + ((size_t)(c0 + c)) * DKD + d4;
    *(short8*)(Po + 0) = w0;
    *(short8*)(Po + 8) = w1;
  } else if (blk < 1058) {
    // zero pad rows 2048..2175 (2 blocks x 64 rows)
    short8 z = {0, 0, 0, 0, 0, 0, 0, 0};
    short* Po = PTbf + ((size_t)SEQ + (blk - 1056) * 64) * DKD + tid * 16;
    *(short8*)(Po + 0) = z;
    *(short8*)(Po + 8) = z;
  } else if (blk < 1570) {
    // zero O: 512 blocks x 256 thr x 16 floats
    const int u = blk - 1058;
    float4 z = {0.f, 0.f, 0.f, 0.f};
    float4* p = (float4*)(Ozero + (size_t)u * 4096 + tid * 16);
    p[0] = z; p[1] = z; p[2] = z; p[3] = z;
  } else {
    // zero L
    const int u = blk - 1570;
    float4 z = {0.f, 0.f, 0.f, 0.f};
    float4* p = (float4*)(Lzero + (size_t)u * 4096 + tid * 16);
    p[0] = z; p[1] = z; p[2] = z; p[3] = z;
  }
}

// ---------- node 2: attention (128-row q-tiles, 4-way key split, 3-panel ring) ----------
__launch_bounds__(NTH, 4)
__global__ void attn_split(const float* __restrict__ Q,
                           const short* __restrict__ Kbf,
                           const short* __restrict__ VTbf,
                           const short* __restrict__ PTbf,
                           float* __restrict__ Oacc,
                           float* __restrict__ Lacc) {
  // 40 KB: Ks 8K + VsT 8K + PsT ring 24K; epilogue reuses as 128x65 f32 (33.3K)
  __shared__ __align__(16) short smem[20480];
  short* Ks  = smem;            // [64][64] K tile  [key][dim], chunk-swizzled
  short* VsT = smem + 4096;     // [64][64] V^T     [dim][sigma(key)]
  short* PsT = smem + 8192;     // [3][64][64] relpos ring [slot][col][dim]

  const int tid = threadIdx.x;
  const int lane = tid & 63;
  const int wave = tid >> 6;
  const int l16 = lane & 15;
  const int quad = lane >> 4;

  // decode: 1024 blocks = 16 qt-slots x (16 batches x 4 quarters), CU-balanced
  const int i = blockIdx.x;
  const int qidx = i >> 6;
  const int s = i & 63;
  const int b = s >> 2;
  const int h = s & 3;
  const int qt = (qidx < 8) ? (15 - qidx) : (qidx - 8);  // 128-row tile index
  const int r0 = qt * 128;
  const int nk = 2 * qt + 2;                  // 64-key tiles covering keys < (qt+1)*128
  const int kt0 = (nk * h) >> 2;
  const int kt1 = (nk * (h + 1)) >> 2;        // [kt0, kt1), may be empty
  const float SC = 0.125f * 1.4426950408889634f;  // (1/sqrt(dk)) * log2(e)

  // ---- persistent pre-scaled Q A-fragments, per strip (rows wave*32 + st*16) ----
  bf16x8 aq[2][2];
  #pragma unroll
  for (int st = 0; st < 2; ++st) {
    const float* Qr = Q + ((size_t)(b * SEQ + r0 + wave * 32 + st * 16 + l16)) * DKD + quad * 8;
    #pragma unroll
    for (int ks = 0; ks < 2; ++ks) {
      float4 x = *(const float4*)(Qr + ks * 32);
      float4 y = *(const float4*)(Qr + ks * 32 + 4);
      bf16x8 t;
      t[0] = f2bf(x.x * SC); t[1] = f2bf(x.y * SC); t[2] = f2bf(x.z * SC); t[3] = f2bf(x.w * SC);
      t[4] = f2bf(y.x * SC); t[5] = f2bf(y.y * SC); t[6] = f2bf(y.z * SC); t[7] = f2bf(y.w * SC);
      aq[st][ks] = t;
    }
  }

  // skew-gather lane tables (per 16-row strip; same for both strips)
  int gsrc[4];
  bool gcar[4];
  #pragma unroll
  for (int r = 0; r < 4; ++r) {
    int o = 15 - (quad * 4 + r);
    int ss = l16 + o;
    gsrc[r] = (quad << 4) | (ss & 15);
    gcar[r] = (ss >= 16);
  }

  // constant MFMA operands
  union i4v { int4 i; bf16x8 v; };
  i4v ONESu; ONESu.i = make_int4(0x3F803F80, 0x3F803F80, 0x3F803F80, 0x3F803F80);
  i4v S0u, S1u;
  S0u.i = make_int4(0, 0, 0, 0);
  S1u.i = make_int4(0, 0, 0, 0);
  if (quad == (l16 >> 2)) {
    const int j = l16 & 3;
    const int val = 0x3F80 << ((j & 1) * 16);
    if (j < 2) { S0u.i.x = val; S1u.i.z = val; }
    else       { S0u.i.y = val; S1u.i.w = val; }
  }

  f32x4 oacc[2][4];  // per strip: O^T tiles, lane = q-in-strip, regs = d
  #pragma unroll
  for (int st = 0; st < 2; ++st)
    #pragma unroll
    for (int t = 0; t < 4; ++t)
      #pragma unroll
      for (int j = 0; j < 4; ++j) oacc[st][t][j] = 0.f;
  f32x4 bl[2];
  #pragma unroll
  for (int st = 0; st < 2; ++st)
    #pragma unroll
    for (int j = 0; j < 4; ++j) bl[st][j] = 0.f;

  for (int kt = kt0; kt < kt1; ++kt) {
    const int j0 = kt * 64;
    const int PL = 30 - 2 * qt + kt;   // ring-low panel (64-aligned window base)
    const int PLmod = PL % 3;
    __syncthreads();

    // ---- DMA staging: K, V^T, relpos panel(s) ----
    #pragma unroll
    for (int half = 0; half < 2; ++half) {
      const int ii = wave * 2 + half;
      const int j = ii * 64 + lane;
      {  // K
        const int k = j >> 3, c8 = (j & 7) ^ (k & 7);
        GLD16(Kbf + ((size_t)(b * SEQ + j0 + k)) * DKD + c8 * 8, Ks + ii * 512);
      }
      {  // V^T (sigma-permuted layout)
        const int d = j >> 3, c8 = (j & 7) ^ (d & 7);
        GLD16(VTbf + ((size_t)(b * DKD + d)) * SEQ + j0 + c8 * 8, VsT + ii * 512);
      }
    }
    {
      const int ii = wave * 2;
      #pragma unroll
      for (int half = 0; half < 2; ++half) {
        const int j = (ii + half) * 64 + lane;
        const int c = j >> 3, c8 = (j & 7) ^ (c & 7);
        // always stage the new high panel
        {
          const int Pg = PL + 2;
          GLD16(PTbf + ((size_t)(Pg * 64 + c)) * DKD + c8 * 8,
                PsT + (Pg % 3) * 4096 + (ii + half) * 512);
        }
        if (kt == kt0) {  // first iter: also the two low panels
          GLD16(PTbf + ((size_t)(PL * 64 + c)) * DKD + c8 * 8,
                PsT + PLmod * 4096 + (ii + half) * 512);
          const int P1 = PL + 1;
          GLD16(PTbf + ((size_t)(P1 * 64 + c)) * DKD + c8 * 8,
                PsT + (P1 % 3) * 4096 + (ii + half) * 512);
        }
      }
    }
    __syncthreads();

    // ---- QK scores, both strips share K fragment reads ----
    f32x4 sacc[2][4];
    #pragma unroll
    for (int st = 0; st < 2; ++st)
      #pragma unroll
      for (int t = 0; t < 4; ++t)
        #pragma unroll
        for (int j = 0; j < 4; ++j) sacc[st][t][j] = 0.f;
    #pragma unroll
    for (int ks = 0; ks < 2; ++ks)
      #pragma unroll
      for (int t = 0; t < 4; ++t) {
        bf16x8 bk = *(const bf16x8*)&Ks[CH(t * 16 + l16, ks * 4 + quad) << 3];
        sacc[0][t] = __builtin_amdgcn_mfma_f32_16x16x32_bf16(aq[0][ks], bk, sacc[0][t], 0, 0, 0);
        sacc[1][t] = __builtin_amdgcn_mfma_f32_16x16x32_bf16(aq[1][ks], bk, sacc[1][t], 0, 0, 0);
      }

    // ---- per strip: bias + gather + mask/exp + transpose -> bpk[st] ----
    i4v bpk[2][2];
    #pragma unroll
    for (int st = 0; st < 2; ++st) {
      const int T0 = 7 - 2 * wave - st;
      const int dj = j0 - (r0 + wave * 32 + st * 16);  // j0 - strip_base
      float g[5][4];
      #pragma unroll
      for (int tt = 0; tt < 5; ++tt) {
        f32x4 bacc;
        #pragma unroll
        for (int j = 0; j < 4; ++j) bacc[j] = 0.f;
        const int T = T0 + tt;
        int sl = PLmod + (T >> 2);
        sl = (sl >= 3) ? sl - 3 : sl;
        const int pc = ((T & 3) << 4) + l16;
        #pragma unroll
        for (int ks = 0; ks < 2; ++ks) {
          bf16x8 bp = *(const bf16x8*)&PsT[sl * 4096 + (CH(pc, ks * 4 + quad) << 3)];
          bacc = __builtin_amdgcn_mfma_f32_16x16x32_bf16(aq[st][ks], bp, bacc, 0, 0, 0);
        }
        #pragma unroll
        for (int r = 0; r < 4; ++r) g[tt][r] = __shfl(bacc[r], gsrc[r], 64);
      }

      const bool dg = (dj > -63);  // mask can only bite when j0+63 > strip_base
      float e[4][4];
      #pragma unroll
      for (int t = 0; t < 4; ++t)
        #pragma unroll
        for (int r = 0; r < 4; ++r) {
          float sc = sacc[st][t][r] + (gcar[r] ? g[t + 1][r] : g[t][r]);
          if (dg && (dj + t * 16 + l16 > quad * 4 + r)) sc = -INFINITY;
          e[t][r] = exp2f(sc);
        }

      i4v ap0, ap1;
      ap0.i.x = pkbf(e[0][1], e[0][0]); ap0.i.y = pkbf(e[0][3], e[0][2]);
      ap0.i.z = pkbf(e[1][1], e[1][0]); ap0.i.w = pkbf(e[1][3], e[1][2]);
      ap1.i.x = pkbf(e[2][1], e[2][0]); ap1.i.y = pkbf(e[2][3], e[2][2]);
      ap1.i.z = pkbf(e[3][1], e[3][0]); ap1.i.w = pkbf(e[3][3], e[3][2]);

      f32x4 zero4;
      #pragma unroll
      for (int j = 0; j < 4; ++j) zero4[j] = 0.f;
      f32x4 Dt[4];
      Dt[0] = __builtin_amdgcn_mfma_f32_16x16x32_bf16(ap0.v, S0u.v, zero4, 0, 0, 0);
      Dt[1] = __builtin_amdgcn_mfma_f32_16x16x32_bf16(ap0.v, S1u.v, zero4, 0, 0, 0);
      Dt[2] = __builtin_amdgcn_mfma_f32_16x16x32_bf16(ap1.v, S0u.v, zero4, 0, 0, 0);
      Dt[3] = __builtin_amdgcn_mfma_f32_16x16x32_bf16(ap1.v, S1u.v, zero4, 0, 0, 0);

      bpk[st][0].i.x = pkbf(Dt[0][1], Dt[0][0]); bpk[st][0].i.y = pkbf(Dt[0][3], Dt[0][2]);
      bpk[st][0].i.z = pkbf(Dt[1][1], Dt[1][0]); bpk[st][0].i.w = pkbf(Dt[1][3], Dt[1][2]);
      bpk[st][1].i.x = pkbf(Dt[2][1], Dt[2][0]); bpk[st][1].i.y = pkbf(Dt[2][3], Dt[2][2]);
      bpk[st][1].i.z = pkbf(Dt[3][1], Dt[3][0]); bpk[st][1].i.w = pkbf(Dt[3][3], Dt[3][2]);
    }

    // ---- PV + rowsum, both strips share V fragment reads ----
    #pragma unroll
    for (int tp = 0; tp < 2; ++tp) {
      bl[0] = __builtin_amdgcn_mfma_f32_16x16x32_bf16(ONESu.v, bpk[0][tp].v, bl[0], 0, 0, 0);
      bl[1] = __builtin_amdgcn_mfma_f32_16x16x32_bf16(ONESu.v, bpk[1][tp].v, bl[1], 0, 0, 0);
      #pragma unroll
      for (int dt = 0; dt < 4; ++dt) {
        bf16x8 av = *(const bf16x8*)&VsT[CH(dt * 16 + l16, tp * 4 + quad) << 3];
        oacc[0][dt] = __builtin_amdgcn_mfma_f32_16x16x32_bf16(av, bpk[0][tp].v, oacc[0][dt], 0, 0, 0);
        oacc[1][dt] = __builtin_amdgcn_mfma_f32_16x16x32_bf16(av, bpk[1][tp].v, oacc[1][dt], 0, 0, 0);
      }
    }
  }

  // ---- epilogue: LDS transpose O^T -> O (128x65), coalesced atomic accumulate ----
  __syncthreads();
  float* Te = (float*)smem;  // 128 x 65 f32 = 33280 B <= 40960
  #pragma unroll
  for (int st = 0; st < 2; ++st)
    #pragma unroll
    for (int dt = 0; dt < 4; ++dt)
      #pragma unroll
      for (int r = 0; r < 4; ++r)
        Te[(wave * 32 + st * 16 + l16) * 65 + dt * 16 + quad * 4 + r] = oacc[st][dt][r];
  __syncthreads();
  if (kt1 > kt0) {
    float* Ob = Oacc + ((size_t)(b * SEQ + r0)) * DKD;
    #pragma unroll
    for (int j = 0; j < 32; ++j) {
      const int idx = j * NTH + tid;       // 0..8191
      const int row = idx >> 6, col = idx & 63;
      unsafeAtomicAdd(&Ob[(size_t)row * DKD + col], Te[row * 65 + col]);
    }
    if (quad == 0) {
      #pragma unroll
      for (int st = 0; st < 2; ++st)
        unsafeAtomicAdd(&Lacc[b * SEQ + r0 + wave * 32 + st * 16 + l16], bl[st][0]);
    }
  }
}

// ---------- node 3: normalize O /= L ----------
__launch_bounds__(NTH)
__global__ void norm_out(float* __restrict__ O, const float* __restrict__ L) {
  const int tid = threadIdx.x;
  const int row = blockIdx.x * 16 + (tid >> 4);
  const int c4 = (tid & 15) << 2;
  const float rl = 1.0f / L[row];
  float4* p = (float4*)(O + (size_t)row * DKD + c4);
  float4 v = *p;
  v.x *= rl; v.y *= rl; v.z *= rl; v.w *= rl;
  *p = v;
}

extern "C" void kernel_launch(void* const* d_in, const int* in_sizes, int n_in,
                              void* d_out, int out_size, void* d_ws, size_t ws_size,
                              hipStream_t stream) {
  const float* Q = (const float*)d_in[0];
  const float* K = (const float*)d_in[1];
  const float* V = (const float*)d_in[2];
  const float* P = (const float*)d_in[3];
  float* O = (float*)d_out;

  short* Kbf = (short*)d_ws;                          // 4,194,304 B
  short* VTbf = (short*)((char*)d_ws + 4194304);      // 4,194,304 B
  short* PTbf = (short*)((char*)d_ws + 8388608);      // 278,528 B
  float* Lacc = (float*)((char*)d_ws + 8667136);      // 131,072 B

  hipLaunchKernelGGL(pre_convert, dim3(1578), dim3(NTH), 0, stream,
                     K, V, P, Kbf, VTbf, PTbf, O, Lacc);
  hipLaunchKernelGGL(attn_split, dim3(1024), dim3(NTH), 0, stream,
                     Q, Kbf, VTbf, PTbf, O, Lacc);
  hipLaunchKernelGGL(norm_out, dim3(BSZ * SEQ / 16), dim3(NTH), 0, stream, O, Lacc);
}

// Round 11
// 154.223 us; speedup vs baseline: 1.1566x; 1.1566x over previous
//
#include <hip/hip_runtime.h>
#include <math.h>

#define BSZ 16
#define SEQ 2048
#define DKD 64
#define NTH 256

typedef __attribute__((ext_vector_type(8))) short bf16x8;
typedef __attribute__((ext_vector_type(8))) short short8;
typedef __attribute__((ext_vector_type(4))) float f32x4;

__device__ __forceinline__ short f2bf(float x) {
  union { float f; unsigned u; } c; c.f = x;
  unsigned r = c.u + 0x7fffu + ((c.u >> 16) & 1u);
  return (short)(r >> 16);
}

// pack two floats' bf16-truncations into one int: low short = lo, high short = hi
__device__ __forceinline__ int pkbf(float hi, float lo) {
  return (int)__builtin_amdgcn_perm(__float_as_uint(hi), __float_as_uint(lo), 0x07060302u);
}

// async 16B/lane global->LDS DMA; ldst wave-uniform, lane i lands at ldst + i*16
#define GLD16(gsrc, ldst)                                                                  \
  __builtin_amdgcn_global_load_lds((const __attribute__((address_space(1))) void*)(gsrc), \
                                   (__attribute__((address_space(3))) void*)(ldst), 16, 0, 0)

// XOR chunk swizzle: logical (row, 16B-chunk c8) -> physical chunk index
#define CH(row, c8) (((row) << 3) + ((c8) ^ ((row) & 7)))

// ws layout: Kbf [16][2048][64] @ 0         (4,194,304 B)
//            VT  [16][64][2048] @ 4194304   (4,194,304 B; keys sigma-permuted per 32)
//            PT  [2112][64]     @ 8388608   (270,336 B; rows 2048..2111 zero)
//            L   [16][2048] f32 @ 8658944   (131,072 B)   total 8,790,016 B

// ---------- node 1: bf16 convert K, transpose+convert V and P, zero O/L ----------
__launch_bounds__(NTH)
__global__ void pre_convert(const float* __restrict__ K, const float* __restrict__ V,
                            const float* __restrict__ P, short* __restrict__ Kbf,
                            short* __restrict__ VTbf, short* __restrict__ PTbf,
                            float* __restrict__ Ozero, float* __restrict__ Lzero) {
  __shared__ short T[64 * 65];
  const int blk = blockIdx.x;
  const int tid = threadIdx.x;
  if (blk < 1024) {
    // K convert (stream) + V transpose, 32-row chunk
    const int b = blk >> 6, ch = blk & 63;
    const float* Kb = K + ((size_t)(b * SEQ + ch * 32)) * DKD;
    const float* Vb = V + ((size_t)(b * SEQ + ch * 32)) * DKD;
    const int r = tid >> 3, c8 = (tid & 7) << 3;
    float4 a0 = *(const float4*)(Kb + r * DKD + c8);
    float4 a1 = *(const float4*)(Kb + r * DKD + c8 + 4);
    short8 ko;
    ko[0] = f2bf(a0.x); ko[1] = f2bf(a0.y); ko[2] = f2bf(a0.z); ko[3] = f2bf(a0.w);
    ko[4] = f2bf(a1.x); ko[5] = f2bf(a1.y); ko[6] = f2bf(a1.z); ko[7] = f2bf(a1.w);
    *(short8*)(Kbf + ((size_t)(b * SEQ + ch * 32 + r)) * DKD + c8) = ko;
    float4 v0 = *(const float4*)(Vb + r * DKD + c8);
    float4 v1 = *(const float4*)(Vb + r * DKD + c8 + 4);
    T[(c8 + 0) * 33 + r] = f2bf(v0.x); T[(c8 + 1) * 33 + r] = f2bf(v0.y);
    T[(c8 + 2) * 33 + r] = f2bf(v0.z); T[(c8 + 3) * 33 + r] = f2bf(v0.w);
    T[(c8 + 4) * 33 + r] = f2bf(v1.x); T[(c8 + 5) * 33 + r] = f2bf(v1.y);
    T[(c8 + 6) * 33 + r] = f2bf(v1.z); T[(c8 + 7) * 33 + r] = f2bf(v1.w);
    __syncthreads();
    // sigma-permuted write: out positions qg*8+j hold keys {4qg..4qg+3, 16+4qg..16+4qg+3}
    const int d = tid >> 2, qg = tid & 3;
    short8 w;
    #pragma unroll
    for (int j = 0; j < 4; ++j) {
      w[j]     = T[d * 33 + qg * 4 + j];
      w[4 + j] = T[d * 33 + 16 + qg * 4 + j];
    }
    *(short8*)(VTbf + ((size_t)(b * DKD + d)) * SEQ + ch * 32 + qg * 8) = w;
  } else if (blk < 1056) {
    const int c0 = (blk - 1024) * 64;
    const int d = tid >> 2, cc4 = (tid & 3) << 4;
    #pragma unroll
    for (int j4 = 0; j4 < 4; ++j4) {
      const int c = cc4 + j4 * 4;
      float4 pv = *(const float4*)(P + (size_t)d * SEQ + c0 + c);
      T[(c + 0) * 65 + d] = f2bf(pv.x);
      T[(c + 1) * 65 + d] = f2bf(pv.y);
      T[(c + 2) * 65 + d] = f2bf(pv.z);
      T[(c + 3) * 65 + d] = f2bf(pv.w);
    }
    __syncthreads();
    const int c = tid >> 2, d4 = (tid & 3) << 4;
    short8 w0, w1;
    #pragma unroll
    for (int j = 0; j < 8; ++j) { w0[j] = T[c * 65 + d4 + j]; w1[j] = T[c * 65 + d4 + 8 + j]; }
    short* Po = PTbf + ((size_t)(c0 + c)) * DKD + d4;
    *(short8*)(Po + 0) = w0;
    *(short8*)(Po + 8) = w1;
  } else if (blk == 1056) {
    short8 z = {0, 0, 0, 0, 0, 0, 0, 0};
    short* Po = PTbf + (size_t)SEQ * DKD + tid * 16;
    *(short8*)(Po + 0) = z;
    *(short8*)(Po + 8) = z;
  } else if (blk < 1569) {
    // zero O: 512 blocks x 256 thr x 16 floats
    const int u = blk - 1057;
    float4 z = {0.f, 0.f, 0.f, 0.f};
    float4* p = (float4*)(Ozero + (size_t)u * 4096 + tid * 16);
    p[0] = z; p[1] = z; p[2] = z; p[3] = z;
  } else {
    // zero L
    const int u = blk - 1569;
    float4 z = {0.f, 0.f, 0.f, 0.f};
    float4* p = (float4*)(Lzero + (size_t)u * 4096 + tid * 16);
    p[0] = z; p[1] = z; p[2] = z; p[3] = z;
  }
}

// ---------- node 2: attention (4-way key split, XCD-pinned batches) ----------
__launch_bounds__(NTH, 5)
__global__ void attn_split(const float* __restrict__ Q,
                           const short* __restrict__ Kbf,
                           const short* __restrict__ VTbf,
                           const short* __restrict__ PTbf,
                           float* __restrict__ Oacc,
                           float* __restrict__ Lacc) {
  // 32 KB staging; epilogue reuses it as a 64x65 f32 transpose buffer
  __shared__ __align__(16) short smem[16384];
  short* Ks  = smem;           // [64][64] K tile  [key][dim], chunk-swizzled
  short* VsT = smem + 4096;    // [64][64] V^T     [dim][sigma(key)]
  short* PsT = smem + 8192;    // [2][64][64] relpos panels [col][dim]

  const int tid = threadIdx.x;
  const int lane = tid & 63;
  const int wave = tid >> 6;
  const int l16 = lane & 15;
  const int quad = lane >> 4;

  // XCD-pinned decode: blockIdx%8 -> XCD (dispatch heuristic); batch b == XCD slot
  // i = 8*t + x: b = x + 8*(t&1), h = (t>>1)&3, qidx = t>>3 (heavy qt first).
  // Per-CU iter sums are exactly 33 for every CU; batches {x, x+8} pin to XCD x.
  const int i = blockIdx.x;
  const int x = i & 7;
  const int t = i >> 3;
  const int b = x + 8 * (t & 1);
  const int h = (t >> 1) & 3;
  const int qidx = t >> 3;
  const int qt = (qidx < 16) ? (31 - qidx) : (qidx - 16);
  const int r0 = qt * 64;
  const int kt0 = ((qt + 1) * h) >> 2;
  const int kt1 = ((qt + 1) * (h + 1)) >> 2;   // [kt0, kt1), may be empty
  const float SC = 0.125f * 1.4426950408889634f;  // (1/sqrt(dk)) * log2(e)

  // ---- persistent pre-scaled Q A-fragments ----
  bf16x8 aq[2];
  {
    const float* Qr = Q + ((size_t)(b * SEQ + r0 + wave * 16 + l16)) * DKD + quad * 8;
    #pragma unroll
    for (int ks = 0; ks < 2; ++ks) {
      float4 xq = *(const float4*)(Qr + ks * 32);
      float4 yq = *(const float4*)(Qr + ks * 32 + 4);
      bf16x8 tq;
      tq[0] = f2bf(xq.x * SC); tq[1] = f2bf(xq.y * SC); tq[2] = f2bf(xq.z * SC); tq[3] = f2bf(xq.w * SC);
      tq[4] = f2bf(yq.x * SC); tq[5] = f2bf(yq.y * SC); tq[6] = f2bf(yq.z * SC); tq[7] = f2bf(yq.w * SC);
      aq[ks] = tq;
    }
  }

  // skew-gather lane tables
  int gsrc[4];
  bool gcar[4];
  #pragma unroll
  for (int r = 0; r < 4; ++r) {
    int o = 15 - (quad * 4 + r);
    int ss = l16 + o;
    gsrc[r] = (quad << 4) | (ss & 15);
    gcar[r] = (ss >= 16);
  }

  // constant MFMA operands: ones-A (rowsum) and transpose selectors S0/S1 (B-frags)
  union i4v { int4 i; bf16x8 v; };
  i4v ONESu; ONESu.i = make_int4(0x3F803F80, 0x3F803F80, 0x3F803F80, 0x3F803F80);
  i4v S0u, S1u;
  S0u.i = make_int4(0, 0, 0, 0);
  S1u.i = make_int4(0, 0, 0, 0);
  if (quad == (l16 >> 2)) {
    const int j = l16 & 3;
    const int val = 0x3F80 << ((j & 1) * 16);
    if (j < 2) { S0u.i.x = val; S1u.i.z = val; }
    else       { S0u.i.y = val; S1u.i.w = val; }
  }

  f32x4 oacc[4];  // O^T tiles: lane = q (strip row wave*16+l16), regs = d
  #pragma unroll
  for (int tt = 0; tt < 4; ++tt)
    #pragma unroll
    for (int j = 0; j < 4; ++j) oacc[tt][j] = 0.f;
  f32x4 bl;  // rowsum: lane = q
  #pragma unroll
  for (int j = 0; j < 4; ++j) bl[j] = 0.f;

  const int Blo0 = 31 - qt;

  for (int kt = kt0; kt < kt1; ++kt) {
    const int j0 = kt * 64;
    __syncthreads();

    // ---- DMA staging ----
    #pragma unroll
    for (int half = 0; half < 2; ++half) {
      const int ii = wave * 2 + half;
      const int j = ii * 64 + lane;
      {  // K
        const int k = j >> 3, c8 = (j & 7) ^ (k & 7);
        GLD16(Kbf + ((size_t)(b * SEQ + j0 + k)) * DKD + c8 * 8, Ks + ii * 512);
      }
      {  // V^T (global layout already sigma-permuted)
        const int d = j >> 3, c8 = (j & 7) ^ (d & 7);
        GLD16(VTbf + ((size_t)(b * DKD + d)) * SEQ + j0 + c8 * 8, VsT + ii * 512);
      }
    }
    {
      const int Bg = Blo0 + kt + 1;
      #pragma unroll
      for (int half = 0; half < 2; ++half) {
        const int ii = wave * 2 + half;
        const int j = ii * 64 + lane;
        const int c = j >> 3, c8 = (j & 7) ^ (c & 7);
        GLD16(PTbf + ((size_t)(Bg * 64 + c)) * DKD + c8 * 8,
              PsT + ((Bg & 1) << 12) + ii * 512);
      }
      if (kt == kt0) {
        const int Bl = Blo0 + kt0;
        #pragma unroll
        for (int half = 0; half < 2; ++half) {
          const int ii = wave * 2 + half;
          const int j = ii * 64 + lane;
          const int c = j >> 3, c8 = (j & 7) ^ (c & 7);
          GLD16(PTbf + ((size_t)(Bl * 64 + c)) * DKD + c8 * 8,
                PsT + ((Bl & 1) << 12) + ii * 512);
        }
      }
    }
    __syncthreads();

    // ---- QK scores: sacc[t] lane = key col, regs = q rows ----
    f32x4 sacc[4];
    #pragma unroll
    for (int tt = 0; tt < 4; ++tt)
      #pragma unroll
      for (int j = 0; j < 4; ++j) sacc[tt][j] = 0.f;
    #pragma unroll
    for (int ks = 0; ks < 2; ++ks)
      #pragma unroll
      for (int tt = 0; tt < 4; ++tt) {
        bf16x8 bk = *(const bf16x8*)&Ks[CH(tt * 16 + l16, ks * 4 + quad) << 3];
        sacc[tt] = __builtin_amdgcn_mfma_f32_16x16x32_bf16(aq[ks], bk, sacc[tt], 0, 0, 0);
      }

    // ---- bias MFMA + immediate skew gather ----
    float g[5][4];
    #pragma unroll
    for (int tt = 0; tt < 5; ++tt) {
      f32x4 bacc;
      #pragma unroll
      for (int j = 0; j < 4; ++j) bacc[j] = 0.f;
      const int c = (tt + 3 - wave) * 16 + l16;
      const int pan = (Blo0 + kt + (c >> 6)) & 1;
      const int pr = c & 63;
      #pragma unroll
      for (int ks = 0; ks < 2; ++ks) {
        bf16x8 bp = *(const bf16x8*)&PsT[(pan << 12) + (CH(pr, ks * 4 + quad) << 3)];
        bacc = __builtin_amdgcn_mfma_f32_16x16x32_bf16(aq[ks], bp, bacc, 0, 0, 0);
      }
      #pragma unroll
      for (int r = 0; r < 4; ++r) g[tt][r] = __shfl(bacc[r], gsrc[r], 64);
    }

    // ---- mask + exp2 (fixed-max) ----
    const bool diag = (kt == qt);
    float e[4][4];
    #pragma unroll
    for (int tt = 0; tt < 4; ++tt)
      #pragma unroll
      for (int r = 0; r < 4; ++r) {
        float sc = sacc[tt][r] + (gcar[r] ? g[tt + 1][r] : g[tt][r]);
        if (diag && (tt * 16 + l16 > wave * 16 + quad * 4 + r)) sc = -INFINITY;
        e[tt][r] = exp2f(sc);
      }

    // ---- pack P as A-frags ----
    i4v ap0, ap1;
    ap0.i.x = pkbf(e[0][1], e[0][0]); ap0.i.y = pkbf(e[0][3], e[0][2]);
    ap0.i.z = pkbf(e[1][1], e[1][0]); ap0.i.w = pkbf(e[1][3], e[1][2]);
    ap1.i.x = pkbf(e[2][1], e[2][0]); ap1.i.y = pkbf(e[2][3], e[2][2]);
    ap1.i.z = pkbf(e[3][1], e[3][0]); ap1.i.w = pkbf(e[3][3], e[3][2]);

    // ---- in-MFMA transpose: Dt[t] = P_t^T ----
    f32x4 zero4;
    #pragma unroll
    for (int j = 0; j < 4; ++j) zero4[j] = 0.f;
    f32x4 Dt[4];
    Dt[0] = __builtin_amdgcn_mfma_f32_16x16x32_bf16(ap0.v, S0u.v, zero4, 0, 0, 0);
    Dt[1] = __builtin_amdgcn_mfma_f32_16x16x32_bf16(ap0.v, S1u.v, zero4, 0, 0, 0);
    Dt[2] = __builtin_amdgcn_mfma_f32_16x16x32_bf16(ap1.v, S0u.v, zero4, 0, 0, 0);
    Dt[3] = __builtin_amdgcn_mfma_f32_16x16x32_bf16(ap1.v, S1u.v, zero4, 0, 0, 0);

    // ---- pack P^T as B-frags ----
    i4v bp0, bp1;
    bp0.i.x = pkbf(Dt[0][1], Dt[0][0]); bp0.i.y = pkbf(Dt[0][3], Dt[0][2]);
    bp0.i.z = pkbf(Dt[1][1], Dt[1][0]); bp0.i.w = pkbf(Dt[1][3], Dt[1][2]);
    bp1.i.x = pkbf(Dt[2][1], Dt[2][0]); bp1.i.y = pkbf(Dt[2][3], Dt[2][2]);
    bp1.i.z = pkbf(Dt[3][1], Dt[3][0]); bp1.i.w = pkbf(Dt[3][3], Dt[3][2]);

    // ---- PV (O^T = V^T * P^T) + rowsum; A-frag = single b128 (sigma layout) ----
    #pragma unroll
    for (int tp = 0; tp < 2; ++tp) {
      const bf16x8 bpk = tp ? bp1.v : bp0.v;
      bl = __builtin_amdgcn_mfma_f32_16x16x32_bf16(ONESu.v, bpk, bl, 0, 0, 0);
      #pragma unroll
      for (int dt = 0; dt < 4; ++dt) {
        bf16x8 av = *(const bf16x8*)&VsT[CH(dt * 16 + l16, tp * 4 + quad) << 3];
        oacc[dt] = __builtin_amdgcn_mfma_f32_16x16x32_bf16(av, bpk, oacc[dt], 0, 0, 0);
      }
    }
  }

  // ---- epilogue: LDS transpose O^T -> O, coalesced atomic accumulate ----
  __syncthreads();  // all waves done with staging buffers
  float* Te = (float*)smem;  // 64 x 65 f32 = 16640 B
  #pragma unroll
  for (int dt = 0; dt < 4; ++dt)
    #pragma unroll
    for (int r = 0; r < 4; ++r)
      Te[(wave * 16 + l16) * 65 + dt * 16 + quad * 4 + r] = oacc[dt][r];
  __syncthreads();
  if (kt1 > kt0) {
    float* Ob = Oacc + ((size_t)(b * SEQ + r0)) * DKD;
    #pragma unroll
    for (int j = 0; j < 16; ++j) {
      const int idx = j * NTH + tid;
      const int row = idx >> 6, col = idx & 63;
      unsafeAtomicAdd(&Ob[(size_t)row * DKD + col], Te[row * 65 + col]);
    }
    if (quad == 0)
      unsafeAtomicAdd(&Lacc[b * SEQ + r0 + wave * 16 + l16], bl[0]);
  }
}

// ---------- node 3: normalize O /= L ----------
__launch_bounds__(NTH)
__global__ void norm_out(float* __restrict__ O, const float* __restrict__ L) {
  const int tid = threadIdx.x;
  const int row = blockIdx.x * 16 + (tid >> 4);
  const int c4 = (tid & 15) << 2;
  const float rl = 1.0f / L[row];
  float4* p = (float4*)(O + (size_t)row * DKD + c4);
  float4 v = *p;
  v.x *= rl; v.y *= rl; v.z *= rl; v.w *= rl;
  *p = v;
}

extern "C" void kernel_launch(void* const* d_in, const int* in_sizes, int n_in,
                              void* d_out, int out_size, void* d_ws, size_t ws_size,
                              hipStream_t stream) {
  const float* Q = (const float*)d_in[0];
  const float* K = (const float*)d_in[1];
  const float* V = (const float*)d_in[2];
  const float* P = (const float*)d_in[3];
  float* O = (float*)d_out;

  short* Kbf = (short*)d_ws;                          // 4,194,304 B
  short* VTbf = (short*)((char*)d_ws + 4194304);      // 4,194,304 B
  short* PTbf = (short*)((char*)d_ws + 8388608);      // 270,336 B
  float* Lacc = (float*)((char*)d_ws + 8658944);      // 131,072 B

  hipLaunchKernelGGL(pre_convert, dim3(1577), dim3(NTH), 0, stream,
                     K, V, P, Kbf, VTbf, PTbf, O, Lacc);
  hipLaunchKernelGGL(attn_split, dim3(2048), dim3(NTH), 0, stream,
                     Q, Kbf, VTbf, PTbf, O, Lacc);
  hipLaunchKernelGGL(norm_out, dim3(BSZ * SEQ / 16), dim3(NTH), 0, stream, O, Lacc);
}

// Round 12
// 152.803 us; speedup vs baseline: 1.1673x; 1.0093x over previous
//
#include <hip/hip_runtime.h>
#include <math.h>

#define BSZ 16
#define SEQ 2048
#define DKD 64
#define NTH 256

typedef __attribute__((ext_vector_type(8))) short bf16x8;
typedef __attribute__((ext_vector_type(8))) short short8;
typedef __attribute__((ext_vector_type(4))) float f32x4;

__device__ __forceinline__ short f2bf(float x) {
  union { float f; unsigned u; } c; c.f = x;
  unsigned r = c.u + 0x7fffu + ((c.u >> 16) & 1u);
  return (short)(r >> 16);
}

// pack two floats' bf16-truncations into one int: low short = lo, high short = hi
__device__ __forceinline__ int pkbf(float hi, float lo) {
  return (int)__builtin_amdgcn_perm(__float_as_uint(hi), __float_as_uint(lo), 0x07060302u);
}

// async 16B/lane global->LDS DMA; ldst wave-uniform, lane i lands at ldst + i*16
#define GLD16(gsrc, ldst)                                                                  \
  __builtin_amdgcn_global_load_lds((const __attribute__((address_space(1))) void*)(gsrc), \
                                   (__attribute__((address_space(3))) void*)(ldst), 16, 0, 0)

// XOR chunk swizzle: logical (row, 16B-chunk c8) -> physical chunk index
#define CH(row, c8) (((row) << 3) + ((c8) ^ ((row) & 7)))

// ws layout: Kbf [16][2048][64] @ 0         (4,194,304 B)
//            VT  [16][64][2048] @ 4194304   (4,194,304 B; keys sigma-permuted per 32)
//            PT  [2112][64]     @ 8388608   (270,336 B; rows 2048..2111 zero)
//            L   [16][2048] f32 @ 8658944   (131,072 B)   total 8,790,016 B

// ---------- node 1: bf16 convert K, transpose+convert V and P, zero O/L ----------
__launch_bounds__(NTH)
__global__ void pre_convert(const float* __restrict__ K, const float* __restrict__ V,
                            const float* __restrict__ P, short* __restrict__ Kbf,
                            short* __restrict__ VTbf, short* __restrict__ PTbf,
                            float* __restrict__ Ozero, float* __restrict__ Lzero) {
  __shared__ short T[64 * 65];
  const int blk = blockIdx.x;
  const int tid = threadIdx.x;
  if (blk < 1024) {
    // K convert (stream) + V transpose, 32-row chunk
    const int b = blk >> 6, ch = blk & 63;
    const float* Kb = K + ((size_t)(b * SEQ + ch * 32)) * DKD;
    const float* Vb = V + ((size_t)(b * SEQ + ch * 32)) * DKD;
    const int r = tid >> 3, c8 = (tid & 7) << 3;
    float4 a0 = *(const float4*)(Kb + r * DKD + c8);
    float4 a1 = *(const float4*)(Kb + r * DKD + c8 + 4);
    short8 ko;
    ko[0] = f2bf(a0.x); ko[1] = f2bf(a0.y); ko[2] = f2bf(a0.z); ko[3] = f2bf(a0.w);
    ko[4] = f2bf(a1.x); ko[5] = f2bf(a1.y); ko[6] = f2bf(a1.z); ko[7] = f2bf(a1.w);
    *(short8*)(Kbf + ((size_t)(b * SEQ + ch * 32 + r)) * DKD + c8) = ko;
    float4 v0 = *(const float4*)(Vb + r * DKD + c8);
    float4 v1 = *(const float4*)(Vb + r * DKD + c8 + 4);
    T[(c8 + 0) * 33 + r] = f2bf(v0.x); T[(c8 + 1) * 33 + r] = f2bf(v0.y);
    T[(c8 + 2) * 33 + r] = f2bf(v0.z); T[(c8 + 3) * 33 + r] = f2bf(v0.w);
    T[(c8 + 4) * 33 + r] = f2bf(v1.x); T[(c8 + 5) * 33 + r] = f2bf(v1.y);
    T[(c8 + 6) * 33 + r] = f2bf(v1.z); T[(c8 + 7) * 33 + r] = f2bf(v1.w);
    __syncthreads();
    // sigma-permuted write: out positions qg*8+j hold keys {4qg..4qg+3, 16+4qg..16+4qg+3}
    const int d = tid >> 2, qg = tid & 3;
    short8 w;
    #pragma unroll
    for (int j = 0; j < 4; ++j) {
      w[j]     = T[d * 33 + qg * 4 + j];
      w[4 + j] = T[d * 33 + 16 + qg * 4 + j];
    }
    *(short8*)(VTbf + ((size_t)(b * DKD + d)) * SEQ + ch * 32 + qg * 8) = w;
  } else if (blk < 1056) {
    const int c0 = (blk - 1024) * 64;
    const int d = tid >> 2, cc4 = (tid & 3) << 4;
    #pragma unroll
    for (int j4 = 0; j4 < 4; ++j4) {
      const int c = cc4 + j4 * 4;
      float4 pv = *(const float4*)(P + (size_t)d * SEQ + c0 + c);
      T[(c + 0) * 65 + d] = f2bf(pv.x);
      T[(c + 1) * 65 + d] = f2bf(pv.y);
      T[(c + 2) * 65 + d] = f2bf(pv.z);
      T[(c + 3) * 65 + d] = f2bf(pv.w);
    }
    __syncthreads();
    const int c = tid >> 2, d4 = (tid & 3) << 4;
    short8 w0, w1;
    #pragma unroll
    for (int j = 0; j < 8; ++j) { w0[j] = T[c * 65 + d4 + j]; w1[j] = T[c * 65 + d4 + 8 + j]; }
    short* Po = PTbf + ((size_t)(c0 + c)) * DKD + d4;
    *(short8*)(Po + 0) = w0;
    *(short8*)(Po + 8) = w1;
  } else if (blk == 1056) {
    short8 z = {0, 0, 0, 0, 0, 0, 0, 0};
    short* Po = PTbf + (size_t)SEQ * DKD + tid * 16;
    *(short8*)(Po + 0) = z;
    *(short8*)(Po + 8) = z;
  } else if (blk < 1569) {
    // zero O: 512 blocks x 256 thr x 16 floats
    const int u = blk - 1057;
    float4 z = {0.f, 0.f, 0.f, 0.f};
    float4* p = (float4*)(Ozero + (size_t)u * 4096 + tid * 16);
    p[0] = z; p[1] = z; p[2] = z; p[3] = z;
  } else {
    // zero L
    const int u = blk - 1569;
    float4 z = {0.f, 0.f, 0.f, 0.f};
    float4* p = (float4*)(Lzero + (size_t)u * 4096 + tid * 16);
    p[0] = z; p[1] = z; p[2] = z; p[3] = z;
  }
}

// ---------- node 2: attention (4-way key split, R9 decode, bias-tile carry) ----------
__launch_bounds__(NTH, 5)
__global__ void attn_split(const float* __restrict__ Q,
                           const short* __restrict__ Kbf,
                           const short* __restrict__ VTbf,
                           const short* __restrict__ PTbf,
                           float* __restrict__ Oacc,
                           float* __restrict__ Lacc) {
  // 32 KB staging; epilogue reuses it as a 64x65 f32 transpose buffer
  __shared__ __align__(16) short smem[16384];
  short* Ks  = smem;           // [64][64] K tile  [key][dim], chunk-swizzled
  short* VsT = smem + 4096;    // [64][64] V^T     [dim][sigma(key)]
  short* PsT = smem + 8192;    // [2][64][64] relpos panels [col][dim]

  const int tid = threadIdx.x;
  const int lane = tid & 63;
  const int wave = tid >> 6;
  const int l16 = lane & 15;
  const int quad = lane >> 4;

  // R9 decode (DO NOT CHANGE: adjacent blocks = same (b,qt), different h ->
  // shared K/V streams in L2 and tight atomic-coalescing window; R10/R11's
  // alternative decodes both exploded FETCH/WRITE 3x)
  const int i = blockIdx.x;
  const int qidx = i >> 6;
  const int s = i & 63;
  const int b = s >> 2;
  const int h = s & 3;
  const int qt = (qidx < 16) ? (31 - qidx) : (qidx - 16);
  const int r0 = qt * 64;
  const int kt0 = ((qt + 1) * h) >> 2;
  const int kt1 = ((qt + 1) * (h + 1)) >> 2;   // [kt0, kt1), may be empty
  const float SC = 0.125f * 1.4426950408889634f;  // (1/sqrt(dk)) * log2(e)

  // ---- persistent pre-scaled Q A-fragments ----
  bf16x8 aq[2];
  {
    const float* Qr = Q + ((size_t)(b * SEQ + r0 + wave * 16 + l16)) * DKD + quad * 8;
    #pragma unroll
    for (int ks = 0; ks < 2; ++ks) {
      float4 xq = *(const float4*)(Qr + ks * 32);
      float4 yq = *(const float4*)(Qr + ks * 32 + 4);
      bf16x8 tq;
      tq[0] = f2bf(xq.x * SC); tq[1] = f2bf(xq.y * SC); tq[2] = f2bf(xq.z * SC); tq[3] = f2bf(xq.w * SC);
      tq[4] = f2bf(yq.x * SC); tq[5] = f2bf(yq.y * SC); tq[6] = f2bf(yq.z * SC); tq[7] = f2bf(yq.w * SC);
      aq[ks] = tq;
    }
  }

  // skew-gather lane tables
  int gsrc[4];
  bool gcar[4];
  #pragma unroll
  for (int r = 0; r < 4; ++r) {
    int o = 15 - (quad * 4 + r);
    int ss = l16 + o;
    gsrc[r] = (quad << 4) | (ss & 15);
    gcar[r] = (ss >= 16);
  }

  // constant MFMA operands: ones-A (rowsum) and transpose selectors S0/S1 (B-frags)
  union i4v { int4 i; bf16x8 v; };
  i4v ONESu; ONESu.i = make_int4(0x3F803F80, 0x3F803F80, 0x3F803F80, 0x3F803F80);
  i4v S0u, S1u;
  S0u.i = make_int4(0, 0, 0, 0);
  S1u.i = make_int4(0, 0, 0, 0);
  if (quad == (l16 >> 2)) {
    const int j = l16 & 3;
    const int val = 0x3F80 << ((j & 1) * 16);
    if (j < 2) { S0u.i.x = val; S1u.i.z = val; }
    else       { S0u.i.y = val; S1u.i.w = val; }
  }

  f32x4 oacc[4];  // O^T tiles: lane = q (strip row wave*16+l16), regs = d
  #pragma unroll
  for (int tt = 0; tt < 4; ++tt)
    #pragma unroll
    for (int j = 0; j < 4; ++j) oacc[tt][j] = 0.f;
  f32x4 bl;  // rowsum: lane = q
  #pragma unroll
  for (int j = 0; j < 4; ++j) bl[j] = 0.f;

  const int Blo0 = 31 - qt;

  // bias column-tile carry: iter kt's tt=4 gather == iter kt+1's tt=0 gather
  float g0c[4];

  for (int kt = kt0; kt < kt1; ++kt) {
    const int j0 = kt * 64;
    __syncthreads();

    // ---- DMA staging ----
    #pragma unroll
    for (int half = 0; half < 2; ++half) {
      const int ii = wave * 2 + half;
      const int j = ii * 64 + lane;
      {  // K
        const int k = j >> 3, c8 = (j & 7) ^ (k & 7);
        GLD16(Kbf + ((size_t)(b * SEQ + j0 + k)) * DKD + c8 * 8, Ks + ii * 512);
      }
      {  // V^T (global layout already sigma-permuted)
        const int d = j >> 3, c8 = (j & 7) ^ (d & 7);
        GLD16(VTbf + ((size_t)(b * DKD + d)) * SEQ + j0 + c8 * 8, VsT + ii * 512);
      }
    }
    {
      const int Bg = Blo0 + kt + 1;
      #pragma unroll
      for (int half = 0; half < 2; ++half) {
        const int ii = wave * 2 + half;
        const int j = ii * 64 + lane;
        const int c = j >> 3, c8 = (j & 7) ^ (c & 7);
        GLD16(PTbf + ((size_t)(Bg * 64 + c)) * DKD + c8 * 8,
              PsT + ((Bg & 1) << 12) + ii * 512);
      }
      if (kt == kt0) {
        const int Bl = Blo0 + kt0;
        #pragma unroll
        for (int half = 0; half < 2; ++half) {
          const int ii = wave * 2 + half;
          const int j = ii * 64 + lane;
          const int c = j >> 3, c8 = (j & 7) ^ (c & 7);
          GLD16(PTbf + ((size_t)(Bl * 64 + c)) * DKD + c8 * 8,
                PsT + ((Bl & 1) << 12) + ii * 512);
        }
      }
    }
    __syncthreads();

    // ---- QK scores: sacc[t] lane = key col, regs = q rows ----
    f32x4 sacc[4];
    #pragma unroll
    for (int tt = 0; tt < 4; ++tt)
      #pragma unroll
      for (int j = 0; j < 4; ++j) sacc[tt][j] = 0.f;
    #pragma unroll
    for (int ks = 0; ks < 2; ++ks)
      #pragma unroll
      for (int tt = 0; tt < 4; ++tt) {
        bf16x8 bk = *(const bf16x8*)&Ks[CH(tt * 16 + l16, ks * 4 + quad) << 3];
        sacc[tt] = __builtin_amdgcn_mfma_f32_16x16x32_bf16(aq[ks], bk, sacc[tt], 0, 0, 0);
      }

    // ---- bias MFMA + immediate skew gather (tt=0 carried from previous iter) ----
    float g[5][4];
    if (kt == kt0) {
      f32x4 bacc;
      #pragma unroll
      for (int j = 0; j < 4; ++j) bacc[j] = 0.f;
      const int c = (3 - wave) * 16 + l16;
      const int pan = (Blo0 + kt + (c >> 6)) & 1;
      const int pr = c & 63;
      #pragma unroll
      for (int ks = 0; ks < 2; ++ks) {
        bf16x8 bp = *(const bf16x8*)&PsT[(pan << 12) + (CH(pr, ks * 4 + quad) << 3)];
        bacc = __builtin_amdgcn_mfma_f32_16x16x32_bf16(aq[ks], bp, bacc, 0, 0, 0);
      }
      #pragma unroll
      for (int r = 0; r < 4; ++r) g[0][r] = __shfl(bacc[r], gsrc[r], 64);
    } else {
      #pragma unroll
      for (int r = 0; r < 4; ++r) g[0][r] = g0c[r];
    }
    #pragma unroll
    for (int tt = 1; tt < 5; ++tt) {
      f32x4 bacc;
      #pragma unroll
      for (int j = 0; j < 4; ++j) bacc[j] = 0.f;
      const int c = (tt + 3 - wave) * 16 + l16;
      const int pan = (Blo0 + kt + (c >> 6)) & 1;
      const int pr = c & 63;
      #pragma unroll
      for (int ks = 0; ks < 2; ++ks) {
        bf16x8 bp = *(const bf16x8*)&PsT[(pan << 12) + (CH(pr, ks * 4 + quad) << 3)];
        bacc = __builtin_amdgcn_mfma_f32_16x16x32_bf16(aq[ks], bp, bacc, 0, 0, 0);
      }
      #pragma unroll
      for (int r = 0; r < 4; ++r) g[tt][r] = __shfl(bacc[r], gsrc[r], 64);
    }
    #pragma unroll
    for (int r = 0; r < 4; ++r) g0c[r] = g[4][r];

    // ---- mask + exp2 (fixed-max) ----
    const bool diag = (kt == qt);
    float e[4][4];
    #pragma unroll
    for (int tt = 0; tt < 4; ++tt)
      #pragma unroll
      for (int r = 0; r < 4; ++r) {
        float sc = sacc[tt][r] + (gcar[r] ? g[tt + 1][r] : g[tt][r]);
        if (diag && (tt * 16 + l16 > wave * 16 + quad * 4 + r)) sc = -INFINITY;
        e[tt][r] = exp2f(sc);
      }

    // ---- pack P as A-frags ----
    i4v ap0, ap1;
    ap0.i.x = pkbf(e[0][1], e[0][0]); ap0.i.y = pkbf(e[0][3], e[0][2]);
    ap0.i.z = pkbf(e[1][1], e[1][0]); ap0.i.w = pkbf(e[1][3], e[1][2]);
    ap1.i.x = pkbf(e[2][1], e[2][0]); ap1.i.y = pkbf(e[2][3], e[2][2]);
    ap1.i.z = pkbf(e[3][1], e[3][0]); ap1.i.w = pkbf(e[3][3], e[3][2]);

    // ---- in-MFMA transpose: Dt[t] = P_t^T ----
    f32x4 zero4;
    #pragma unroll
    for (int j = 0; j < 4; ++j) zero4[j] = 0.f;
    f32x4 Dt[4];
    Dt[0] = __builtin_amdgcn_mfma_f32_16x16x32_bf16(ap0.v, S0u.v, zero4, 0, 0, 0);
    Dt[1] = __builtin_amdgcn_mfma_f32_16x16x32_bf16(ap0.v, S1u.v, zero4, 0, 0, 0);
    Dt[2] = __builtin_amdgcn_mfma_f32_16x16x32_bf16(ap1.v, S0u.v, zero4, 0, 0, 0);
    Dt[3] = __builtin_amdgcn_mfma_f32_16x16x32_bf16(ap1.v, S1u.v, zero4, 0, 0, 0);

    // ---- pack P^T as B-frags ----
    i4v bp0, bp1;
    bp0.i.x = pkbf(Dt[0][1], Dt[0][0]); bp0.i.y = pkbf(Dt[0][3], Dt[0][2]);
    bp0.i.z = pkbf(Dt[1][1], Dt[1][0]); bp0.i.w = pkbf(Dt[1][3], Dt[1][2]);
    bp1.i.x = pkbf(Dt[2][1], Dt[2][0]); bp1.i.y = pkbf(Dt[2][3], Dt[2][2]);
    bp1.i.z = pkbf(Dt[3][1], Dt[3][0]); bp1.i.w = pkbf(Dt[3][3], Dt[3][2]);

    // ---- PV (O^T = V^T * P^T) + rowsum; A-frag = single b128 (sigma layout) ----
    #pragma unroll
    for (int tp = 0; tp < 2; ++tp) {
      const bf16x8 bpk = tp ? bp1.v : bp0.v;
      bl = __builtin_amdgcn_mfma_f32_16x16x32_bf16(ONESu.v, bpk, bl, 0, 0, 0);
      #pragma unroll
      for (int dt = 0; dt < 4; ++dt) {
        bf16x8 av = *(const bf16x8*)&VsT[CH(dt * 16 + l16, tp * 4 + quad) << 3];
        oacc[dt] = __builtin_amdgcn_mfma_f32_16x16x32_bf16(av, bpk, oacc[dt], 0, 0, 0);
      }
    }
  }

  // ---- epilogue: LDS transpose O^T -> O, coalesced atomic accumulate ----
  __syncthreads();  // all waves done with staging buffers
  float* Te = (float*)smem;  // 64 x 65 f32 = 16640 B
  #pragma unroll
  for (int dt = 0; dt < 4; ++dt)
    #pragma unroll
    for (int r = 0; r < 4; ++r)
      Te[(wave * 16 + l16) * 65 + dt * 16 + quad * 4 + r] = oacc[dt][r];
  __syncthreads();
  if (kt1 > kt0) {
    float* Ob = Oacc + ((size_t)(b * SEQ + r0)) * DKD;
    #pragma unroll
    for (int j = 0; j < 16; ++j) {
      const int idx = j * NTH + tid;
      const int row = idx >> 6, col = idx & 63;
      unsafeAtomicAdd(&Ob[(size_t)row * DKD + col], Te[row * 65 + col]);
    }
    if (quad == 0)
      unsafeAtomicAdd(&Lacc[b * SEQ + r0 + wave * 16 + l16], bl[0]);
  }
}

// ---------- node 3: normalize O /= L ----------
__launch_bounds__(NTH)
__global__ void norm_out(float* __restrict__ O, const float* __restrict__ L) {
  const int tid = threadIdx.x;
  const int row = blockIdx.x * 16 + (tid >> 4);
  const int c4 = (tid & 15) << 2;
  const float rl = 1.0f / L[row];
  float4* p = (float4*)(O + (size_t)row * DKD + c4);
  float4 v = *p;
  v.x *= rl; v.y *= rl; v.z *= rl; v.w *= rl;
  *p = v;
}

extern "C" void kernel_launch(void* const* d_in, const int* in_sizes, int n_in,
                              void* d_out, int out_size, void* d_ws, size_t ws_size,
                              hipStream_t stream) {
  const float* Q = (const float*)d_in[0];
  const float* K = (const float*)d_in[1];
  const float* V = (const float*)d_in[2];
  const float* P = (const float*)d_in[3];
  float* O = (float*)d_out;

  short* Kbf = (short*)d_ws;                          // 4,194,304 B
  short* VTbf = (short*)((char*)d_ws + 4194304);      // 4,194,304 B
  short* PTbf = (short*)((char*)d_ws + 8388608);      // 270,336 B
  float* Lacc = (float*)((char*)d_ws + 8658944);      // 131,072 B

  hipLaunchKernelGGL(pre_convert, dim3(1577), dim3(NTH), 0, stream,
                     K, V, P, Kbf, VTbf, PTbf, O, Lacc);
  hipLaunchKernelGGL(attn_split, dim3(2048), dim3(NTH), 0, stream,
                     Q, Kbf, VTbf, PTbf, O, Lacc);
  hipLaunchKernelGGL(norm_out, dim3(BSZ * SEQ / 16), dim3(NTH), 0, stream, O, Lacc);
}

// Round 13
// 125.413 us; speedup vs baseline: 1.4223x; 1.2184x over previous
//
#include <hip/hip_runtime.h>
#include <math.h>

#define BSZ 16
#define SEQ 2048
#define DKD 64
#define NTH 256

typedef __attribute__((ext_vector_type(8))) short bf16x8;
typedef __attribute__((ext_vector_type(8))) short short8;
typedef __attribute__((ext_vector_type(4))) float f32x4;

__device__ __forceinline__ short f2bf(float x) {
  union { float f; unsigned u; } c; c.f = x;
  unsigned r = c.u + 0x7fffu + ((c.u >> 16) & 1u);
  return (short)(r >> 16);
}

// pack two floats' bf16-truncations into one int: low short = lo, high short = hi
__device__ __forceinline__ int pkbf(float hi, float lo) {
  return (int)__builtin_amdgcn_perm(__float_as_uint(hi), __float_as_uint(lo), 0x07060302u);
}

// async 16B/lane global->LDS DMA; ldst wave-uniform, lane i lands at ldst + i*16
#define GLD16(gsrc, ldst)                                                                  \
  __builtin_amdgcn_global_load_lds((const __attribute__((address_space(1))) void*)(gsrc), \
                                   (__attribute__((address_space(3))) void*)(ldst), 16, 0, 0)

// XOR chunk swizzle: logical (row, 16B-chunk c8) -> physical chunk index
#define CH(row, c8) (((row) << 3) + ((c8) ^ ((row) & 7)))

// ws layout: Kbf [16][2048][64] @ 0         (4,194,304 B)
//            VT  [16][64][2048] @ 4194304   (4,194,304 B; keys sigma-permuted per 32)
//            PT  [2112][64]     @ 8388608   (270,336 B; rows 2048..2111 zero)
//            L   [16][2048] f32 @ 8658944   (131,072 B)   total 8,790,016 B

// ---------- node 1: bf16 convert K, transpose+convert V and P, zero O/L ----------
__launch_bounds__(NTH)
__global__ void pre_convert(const float* __restrict__ K, const float* __restrict__ V,
                            const float* __restrict__ P, short* __restrict__ Kbf,
                            short* __restrict__ VTbf, short* __restrict__ PTbf,
                            float* __restrict__ Ozero, float* __restrict__ Lzero) {
  __shared__ short T[64 * 65];
  const int blk = blockIdx.x;
  const int tid = threadIdx.x;
  if (blk < 1024) {
    // K convert (stream) + V transpose, 32-row chunk
    const int b = blk >> 6, ch = blk & 63;
    const float* Kb = K + ((size_t)(b * SEQ + ch * 32)) * DKD;
    const float* Vb = V + ((size_t)(b * SEQ + ch * 32)) * DKD;
    const int r = tid >> 3, c8 = (tid & 7) << 3;
    float4 a0 = *(const float4*)(Kb + r * DKD + c8);
    float4 a1 = *(const float4*)(Kb + r * DKD + c8 + 4);
    short8 ko;
    ko[0] = f2bf(a0.x); ko[1] = f2bf(a0.y); ko[2] = f2bf(a0.z); ko[3] = f2bf(a0.w);
    ko[4] = f2bf(a1.x); ko[5] = f2bf(a1.y); ko[6] = f2bf(a1.z); ko[7] = f2bf(a1.w);
    *(short8*)(Kbf + ((size_t)(b * SEQ + ch * 32 + r)) * DKD + c8) = ko;
    float4 v0 = *(const float4*)(Vb + r * DKD + c8);
    float4 v1 = *(const float4*)(Vb + r * DKD + c8 + 4);
    T[(c8 + 0) * 33 + r] = f2bf(v0.x); T[(c8 + 1) * 33 + r] = f2bf(v0.y);
    T[(c8 + 2) * 33 + r] = f2bf(v0.z); T[(c8 + 3) * 33 + r] = f2bf(v0.w);
    T[(c8 + 4) * 33 + r] = f2bf(v1.x); T[(c8 + 5) * 33 + r] = f2bf(v1.y);
    T[(c8 + 6) * 33 + r] = f2bf(v1.z); T[(c8 + 7) * 33 + r] = f2bf(v1.w);
    __syncthreads();
    // sigma-permuted write: out positions qg*8+j hold keys {4qg..4qg+3, 16+4qg..16+4qg+3}
    const int d = tid >> 2, qg = tid & 3;
    short8 w;
    #pragma unroll
    for (int j = 0; j < 4; ++j) {
      w[j]     = T[d * 33 + qg * 4 + j];
      w[4 + j] = T[d * 33 + 16 + qg * 4 + j];
    }
    *(short8*)(VTbf + ((size_t)(b * DKD + d)) * SEQ + ch * 32 + qg * 8) = w;
  } else if (blk < 1056) {
    const int c0 = (blk - 1024) * 64;
    const int d = tid >> 2, cc4 = (tid & 3) << 4;
    #pragma unroll
    for (int j4 = 0; j4 < 4; ++j4) {
      const int c = cc4 + j4 * 4;
      float4 pv = *(const float4*)(P + (size_t)d * SEQ + c0 + c);
      T[(c + 0) * 65 + d] = f2bf(pv.x);
      T[(c + 1) * 65 + d] = f2bf(pv.y);
      T[(c + 2) * 65 + d] = f2bf(pv.z);
      T[(c + 3) * 65 + d] = f2bf(pv.w);
    }
    __syncthreads();
    const int c = tid >> 2, d4 = (tid & 3) << 4;
    short8 w0, w1;
    #pragma unroll
    for (int j = 0; j < 8; ++j) { w0[j] = T[c * 65 + d4 + j]; w1[j] = T[c * 65 + d4 + 8 + j]; }
    short* Po = PTbf + ((size_t)(c0 + c)) * DKD + d4;
    *(short8*)(Po + 0) = w0;
    *(short8*)(Po + 8) = w1;
  } else if (blk == 1056) {
    short8 z = {0, 0, 0, 0, 0, 0, 0, 0};
    short* Po = PTbf + (size_t)SEQ * DKD + tid * 16;
    *(short8*)(Po + 0) = z;
    *(short8*)(Po + 8) = z;
  } else if (blk < 1569) {
    // zero O: 512 blocks x 256 thr x 16 floats
    const int u = blk - 1057;
    float4 z = {0.f, 0.f, 0.f, 0.f};
    float4* p = (float4*)(Ozero + (size_t)u * 4096 + tid * 16);
    p[0] = z; p[1] = z; p[2] = z; p[3] = z;
  } else {
    // zero L
    const int u = blk - 1569;
    float4 z = {0.f, 0.f, 0.f, 0.f};
    float4* p = (float4*)(Lzero + (size_t)u * 4096 + tid * 16);
    p[0] = z; p[1] = z; p[2] = z; p[3] = z;
  }
}

// ---------- node 2: attention (4-way key split, R9 schedule, bias-tile carry) ----------
// DO NOT CHANGE decode or launch_bounds: R10 (128-tile), R11 (XCD decode), and
// R12 (5 blocks/CU) all broke the L2 temporal alignment of the 4 h-quarters
// sharing K/V streams -> FETCH 30->95..144 MB, attn 53->82..101 us.
__launch_bounds__(NTH, 4)
__global__ void attn_split(const float* __restrict__ Q,
                           const short* __restrict__ Kbf,
                           const short* __restrict__ VTbf,
                           const short* __restrict__ PTbf,
                           float* __restrict__ Oacc,
                           float* __restrict__ Lacc) {
  // 32 KB staging; epilogue reuses it as a 64x65 f32 transpose buffer
  __shared__ __align__(16) short smem[16384];
  short* Ks  = smem;           // [64][64] K tile  [key][dim], chunk-swizzled
  short* VsT = smem + 4096;    // [64][64] V^T     [dim][sigma(key)]
  short* PsT = smem + 8192;    // [2][64][64] relpos panels [col][dim]

  const int tid = threadIdx.x;
  const int lane = tid & 63;
  const int wave = tid >> 6;
  const int l16 = lane & 15;
  const int quad = lane >> 4;

  const int i = blockIdx.x;
  const int qidx = i >> 6;
  const int s = i & 63;
  const int b = s >> 2;
  const int h = s & 3;
  const int qt = (qidx < 16) ? (31 - qidx) : (qidx - 16);
  const int r0 = qt * 64;
  const int kt0 = ((qt + 1) * h) >> 2;
  const int kt1 = ((qt + 1) * (h + 1)) >> 2;   // [kt0, kt1), may be empty
  const float SC = 0.125f * 1.4426950408889634f;  // (1/sqrt(dk)) * log2(e)

  // ---- persistent pre-scaled Q A-fragments ----
  bf16x8 aq[2];
  {
    const float* Qr = Q + ((size_t)(b * SEQ + r0 + wave * 16 + l16)) * DKD + quad * 8;
    #pragma unroll
    for (int ks = 0; ks < 2; ++ks) {
      float4 xq = *(const float4*)(Qr + ks * 32);
      float4 yq = *(const float4*)(Qr + ks * 32 + 4);
      bf16x8 tq;
      tq[0] = f2bf(xq.x * SC); tq[1] = f2bf(xq.y * SC); tq[2] = f2bf(xq.z * SC); tq[3] = f2bf(xq.w * SC);
      tq[4] = f2bf(yq.x * SC); tq[5] = f2bf(yq.y * SC); tq[6] = f2bf(yq.z * SC); tq[7] = f2bf(yq.w * SC);
      aq[ks] = tq;
    }
  }

  // skew-gather lane tables
  int gsrc[4];
  bool gcar[4];
  #pragma unroll
  for (int r = 0; r < 4; ++r) {
    int o = 15 - (quad * 4 + r);
    int ss = l16 + o;
    gsrc[r] = (quad << 4) | (ss & 15);
    gcar[r] = (ss >= 16);
  }

  // constant MFMA operands: ones-A (rowsum) and transpose selectors S0/S1 (B-frags)
  union i4v { int4 i; bf16x8 v; };
  i4v ONESu; ONESu.i = make_int4(0x3F803F80, 0x3F803F80, 0x3F803F80, 0x3F803F80);
  i4v S0u, S1u;
  S0u.i = make_int4(0, 0, 0, 0);
  S1u.i = make_int4(0, 0, 0, 0);
  if (quad == (l16 >> 2)) {
    const int j = l16 & 3;
    const int val = 0x3F80 << ((j & 1) * 16);
    if (j < 2) { S0u.i.x = val; S1u.i.z = val; }
    else       { S0u.i.y = val; S1u.i.w = val; }
  }

  f32x4 oacc[4];  // O^T tiles: lane = q (strip row wave*16+l16), regs = d
  #pragma unroll
  for (int tt = 0; tt < 4; ++tt)
    #pragma unroll
    for (int j = 0; j < 4; ++j) oacc[tt][j] = 0.f;
  f32x4 bl;  // rowsum: lane = q
  #pragma unroll
  for (int j = 0; j < 4; ++j) bl[j] = 0.f;

  const int Blo0 = 31 - qt;

  // bias column-tile carry: iter kt's tt=4 gather == iter kt+1's tt=0 gather
  float g0c[4];

  for (int kt = kt0; kt < kt1; ++kt) {
    const int j0 = kt * 64;
    __syncthreads();

    // ---- DMA staging ----
    #pragma unroll
    for (int half = 0; half < 2; ++half) {
      const int ii = wave * 2 + half;
      const int j = ii * 64 + lane;
      {  // K
        const int k = j >> 3, c8 = (j & 7) ^ (k & 7);
        GLD16(Kbf + ((size_t)(b * SEQ + j0 + k)) * DKD + c8 * 8, Ks + ii * 512);
      }
      {  // V^T (global layout already sigma-permuted)
        const int d = j >> 3, c8 = (j & 7) ^ (d & 7);
        GLD16(VTbf + ((size_t)(b * DKD + d)) * SEQ + j0 + c8 * 8, VsT + ii * 512);
      }
    }
    {
      const int Bg = Blo0 + kt + 1;
      #pragma unroll
      for (int half = 0; half < 2; ++half) {
        const int ii = wave * 2 + half;
        const int j = ii * 64 + lane;
        const int c = j >> 3, c8 = (j & 7) ^ (c & 7);
        GLD16(PTbf + ((size_t)(Bg * 64 + c)) * DKD + c8 * 8,
              PsT + ((Bg & 1) << 12) + ii * 512);
      }
      if (kt == kt0) {
        const int Bl = Blo0 + kt0;
        #pragma unroll
        for (int half = 0; half < 2; ++half) {
          const int ii = wave * 2 + half;
          const int j = ii * 64 + lane;
          const int c = j >> 3, c8 = (j & 7) ^ (c & 7);
          GLD16(PTbf + ((size_t)(Bl * 64 + c)) * DKD + c8 * 8,
                PsT + ((Bl & 1) << 12) + ii * 512);
        }
      }
    }
    __syncthreads();

    // ---- QK scores: sacc[t] lane = key col, regs = q rows ----
    f32x4 sacc[4];
    #pragma unroll
    for (int tt = 0; tt < 4; ++tt)
      #pragma unroll
      for (int j = 0; j < 4; ++j) sacc[tt][j] = 0.f;
    #pragma unroll
    for (int ks = 0; ks < 2; ++ks)
      #pragma unroll
      for (int tt = 0; tt < 4; ++tt) {
        bf16x8 bk = *(const bf16x8*)&Ks[CH(tt * 16 + l16, ks * 4 + quad) << 3];
        sacc[tt] = __builtin_amdgcn_mfma_f32_16x16x32_bf16(aq[ks], bk, sacc[tt], 0, 0, 0);
      }

    // ---- bias MFMA + immediate skew gather (tt=0 carried from previous iter) ----
    float g[5][4];
    if (kt == kt0) {
      f32x4 bacc;
      #pragma unroll
      for (int j = 0; j < 4; ++j) bacc[j] = 0.f;
      const int c = (3 - wave) * 16 + l16;
      const int pan = (Blo0 + kt + (c >> 6)) & 1;
      const int pr = c & 63;
      #pragma unroll
      for (int ks = 0; ks < 2; ++ks) {
        bf16x8 bp = *(const bf16x8*)&PsT[(pan << 12) + (CH(pr, ks * 4 + quad) << 3)];
        bacc = __builtin_amdgcn_mfma_f32_16x16x32_bf16(aq[ks], bp, bacc, 0, 0, 0);
      }
      #pragma unroll
      for (int r = 0; r < 4; ++r) g[0][r] = __shfl(bacc[r], gsrc[r], 64);
    } else {
      #pragma unroll
      for (int r = 0; r < 4; ++r) g[0][r] = g0c[r];
    }
    #pragma unroll
    for (int tt = 1; tt < 5; ++tt) {
      f32x4 bacc;
      #pragma unroll
      for (int j = 0; j < 4; ++j) bacc[j] = 0.f;
      const int c = (tt + 3 - wave) * 16 + l16;
      const int pan = (Blo0 + kt + (c >> 6)) & 1;
      const int pr = c & 63;
      #pragma unroll
      for (int ks = 0; ks < 2; ++ks) {
        bf16x8 bp = *(const bf16x8*)&PsT[(pan << 12) + (CH(pr, ks * 4 + quad) << 3)];
        bacc = __builtin_amdgcn_mfma_f32_16x16x32_bf16(aq[ks], bp, bacc, 0, 0, 0);
      }
      #pragma unroll
      for (int r = 0; r < 4; ++r) g[tt][r] = __shfl(bacc[r], gsrc[r], 64);
    }
    #pragma unroll
    for (int r = 0; r < 4; ++r) g0c[r] = g[4][r];

    // ---- mask + exp2 (fixed-max) ----
    const bool diag = (kt == qt);
    float e[4][4];
    #pragma unroll
    for (int tt = 0; tt < 4; ++tt)
      #pragma unroll
      for (int r = 0; r < 4; ++r) {
        float sc = sacc[tt][r] + (gcar[r] ? g[tt + 1][r] : g[tt][r]);
        if (diag && (tt * 16 + l16 > wave * 16 + quad * 4 + r)) sc = -INFINITY;
        e[tt][r] = exp2f(sc);
      }

    // ---- pack P as A-frags ----
    i4v ap0, ap1;
    ap0.i.x = pkbf(e[0][1], e[0][0]); ap0.i.y = pkbf(e[0][3], e[0][2]);
    ap0.i.z = pkbf(e[1][1], e[1][0]); ap0.i.w = pkbf(e[1][3], e[1][2]);
    ap1.i.x = pkbf(e[2][1], e[2][0]); ap1.i.y = pkbf(e[2][3], e[2][2]);
    ap1.i.z = pkbf(e[3][1], e[3][0]); ap1.i.w = pkbf(e[3][3], e[3][2]);

    // ---- in-MFMA transpose: Dt[t] = P_t^T ----
    f32x4 zero4;
    #pragma unroll
    for (int j = 0; j < 4; ++j) zero4[j] = 0.f;
    f32x4 Dt[4];
    Dt[0] = __builtin_amdgcn_mfma_f32_16x16x32_bf16(ap0.v, S0u.v, zero4, 0, 0, 0);
    Dt[1] = __builtin_amdgcn_mfma_f32_16x16x32_bf16(ap0.v, S1u.v, zero4, 0, 0, 0);
    Dt[2] = __builtin_amdgcn_mfma_f32_16x16x32_bf16(ap1.v, S0u.v, zero4, 0, 0, 0);
    Dt[3] = __builtin_amdgcn_mfma_f32_16x16x32_bf16(ap1.v, S1u.v, zero4, 0, 0, 0);

    // ---- pack P^T as B-frags ----
    i4v bp0, bp1;
    bp0.i.x = pkbf(Dt[0][1], Dt[0][0]); bp0.i.y = pkbf(Dt[0][3], Dt[0][2]);
    bp0.i.z = pkbf(Dt[1][1], Dt[1][0]); bp0.i.w = pkbf(Dt[1][3], Dt[1][2]);
    bp1.i.x = pkbf(Dt[2][1], Dt[2][0]); bp1.i.y = pkbf(Dt[2][3], Dt[2][2]);
    bp1.i.z = pkbf(Dt[3][1], Dt[3][0]); bp1.i.w = pkbf(Dt[3][3], Dt[3][2]);

    // ---- PV (O^T = V^T * P^T) + rowsum; A-frag = single b128 (sigma layout) ----
    #pragma unroll
    for (int tp = 0; tp < 2; ++tp) {
      const bf16x8 bpk = tp ? bp1.v : bp0.v;
      bl = __builtin_amdgcn_mfma_f32_16x16x32_bf16(ONESu.v, bpk, bl, 0, 0, 0);
      #pragma unroll
      for (int dt = 0; dt < 4; ++dt) {
        bf16x8 av = *(const bf16x8*)&VsT[CH(dt * 16 + l16, tp * 4 + quad) << 3];
        oacc[dt] = __builtin_amdgcn_mfma_f32_16x16x32_bf16(av, bpk, oacc[dt], 0, 0, 0);
      }
    }
  }

  // ---- epilogue: LDS transpose O^T -> O, coalesced atomic accumulate ----
  __syncthreads();  // all waves done with staging buffers
  float* Te = (float*)smem;  // 64 x 65 f32 = 16640 B
  #pragma unroll
  for (int dt = 0; dt < 4; ++dt)
    #pragma unroll
    for (int r = 0; r < 4; ++r)
      Te[(wave * 16 + l16) * 65 + dt * 16 + quad * 4 + r] = oacc[dt][r];
  __syncthreads();
  if (kt1 > kt0) {
    float* Ob = Oacc + ((size_t)(b * SEQ + r0)) * DKD;
    #pragma unroll
    for (int j = 0; j < 16; ++j) {
      const int idx = j * NTH + tid;
      const int row = idx >> 6, col = idx & 63;
      unsafeAtomicAdd(&Ob[(size_t)row * DKD + col], Te[row * 65 + col]);
    }
    if (quad == 0)
      unsafeAtomicAdd(&Lacc[b * SEQ + r0 + wave * 16 + l16], bl[0]);
  }
}

// ---------- node 3: normalize O /= L ----------
__launch_bounds__(NTH)
__global__ void norm_out(float* __restrict__ O, const float* __restrict__ L) {
  const int tid = threadIdx.x;
  const int row = blockIdx.x * 16 + (tid >> 4);
  const int c4 = (tid & 15) << 2;
  const float rl = 1.0f / L[row];
  float4* p = (float4*)(O + (size_t)row * DKD + c4);
  float4 v = *p;
  v.x *= rl; v.y *= rl; v.z *= rl; v.w *= rl;
  *p = v;
}

extern "C" void kernel_launch(void* const* d_in, const int* in_sizes, int n_in,
                              void* d_out, int out_size, void* d_ws, size_t ws_size,
                              hipStream_t stream) {
  const float* Q = (const float*)d_in[0];
  const float* K = (const float*)d_in[1];
  const float* V = (const float*)d_in[2];
  const float* P = (const float*)d_in[3];
  float* O = (float*)d_out;

  short* Kbf = (short*)d_ws;                          // 4,194,304 B
  short* VTbf = (short*)((char*)d_ws + 4194304);      // 4,194,304 B
  short* PTbf = (short*)((char*)d_ws + 8388608);      // 270,336 B
  float* Lacc = (float*)((char*)d_ws + 8658944);      // 131,072 B

  hipLaunchKernelGGL(pre_convert, dim3(1577), dim3(NTH), 0, stream,
                     K, V, P, Kbf, VTbf, PTbf, O, Lacc);
  hipLaunchKernelGGL(attn_split, dim3(2048), dim3(NTH), 0, stream,
                     Q, Kbf, VTbf, PTbf, O, Lacc);
  hipLaunchKernelGGL(norm_out, dim3(BSZ * SEQ / 16), dim3(NTH), 0, stream, O, Lacc);
}